// Round 3
// baseline (200.803 us; speedup 1.0000x reference)
//
#include <hip/hip_runtime.h>

// Problem constants
#define BB 4
#define CC 16
#define HH 256
#define WW 256
#define NN (HH*WW)      // 65536
#define SS 100
#define NSLOT 16        // partial slots per (b,q): 16 n-chunks
#define EPSV 1e-32f

// ws layout (float offsets)
#define PPART_OFF 80000u                  // [B*2][NSLOT][C][S]      = 204800
#define QSUM_OFF  284800u                 // [B*2][NSLOT][S]         = 12800
#define SPFN_OFF  297600u                 // [B*2][C][S]             = 12800
#define PFSP_OFF  310400u                 // [B][C][N]               = 4194304
// total 4504704 floats = 18.0 MB

__device__ __forceinline__ float dot4(const float4& a, const float4& b) {
    return a.x * b.x + a.y * b.y + a.z * b.z + a.w * b.w;
}
__device__ __forceinline__ void fma4(float4& a, float s, const float4& v) {
    a.x += s * v.x; a.y += s * v.y; a.z += s * v.z; a.w += s * v.w;
}

// ---- pass1 helpers: fully-unrolled load / fma on register buffers ----
__device__ __forceinline__ void p1_load(float4 qv[5], float4 pv[4],
        const float* const qr[5], const float* const pr[4], int off) {
    #pragma unroll
    for (int si = 0; si < 5; ++si) qv[si] = *(const float4*)(qr[si] + off);
    #pragma unroll
    for (int ci = 0; ci < 4; ++ci) pv[ci] = *(const float4*)(pr[ci] + off);
}
__device__ __forceinline__ void p1_fma(float acc[4][5], float qs[5],
        const float4 qv[5], const float4 pv[4]) {
    #pragma unroll
    for (int ci = 0; ci < 4; ++ci)
        #pragma unroll
        for (int si = 0; si < 5; ++si)
            acc[ci][si] += dot4(pv[ci], qv[si]);
    #pragma unroll
    for (int si = 0; si < 5; ++si)
        qs[si] += qv[si].x + qv[si].y + qv[si].z + qv[si].w;
}

// K2: partial P[c,s] = sum_n pf[c,n]*Q[s,n], qsum[s] = sum_n Q[s,n]
// Register GEMM, no LDS, branchless hot loop, explicit 2-deep pipeline.
// Block = 4 waves = 4 c-quads, all sharing the same 5 s-rows and n-chunk.
// Grid: x = s-tile (20), y = chunk (16 x 4096), z = bq (8).
__global__ __launch_bounds__(256) void k_pass1(const float* __restrict__ pf,
                                               const float* __restrict__ Q1,
                                               const float* __restrict__ Q2,
                                               float* __restrict__ ws) {
    int stile = blockIdx.x;   // 0..19
    int chunk = blockIdx.y;   // 0..15
    int bq    = blockIdx.z;   // 0..7
    int b = bq >> 1, q = bq & 1;
    const float* Q  = (q ? Q2 : Q1) + (size_t)b * SS * NN;
    const float* PF = pf + (size_t)b * CC * NN;

    int tid = threadIdx.x, w = tid >> 6, lane = tid & 63;
    int cbase = w * 4, sbase = stile * 5;
    int nbase = chunk * 4096 + lane * 4;

    const float* qr[5];
    const float* pr[4];
    #pragma unroll
    for (int si = 0; si < 5; ++si) qr[si] = Q + (size_t)(sbase + si) * NN + nbase;
    #pragma unroll
    for (int ci = 0; ci < 4; ++ci) pr[ci] = PF + (size_t)(cbase + ci) * NN + nbase;

    float acc[4][5] = {};
    float qs[5] = {};
    float4 qa[5], pa[4], qb[5], pb[4];

    p1_load(qa, pa, qr, pr, 0);
    for (int k = 0; k < 16; k += 2) {
        p1_load(qb, pb, qr, pr, (k + 1) * 256);
        p1_fma(acc, qs, qa, pa);
        p1_load(qa, pa, qr, pr, ((k + 2) & 15) * 256);   // wraps to 0 on last iter (in-bounds)
        p1_fma(acc, qs, qb, pb);
    }

    // 64-lane butterfly reduction (25 values)
    #pragma unroll
    for (int m = 1; m < 64; m <<= 1) {
        #pragma unroll
        for (int ci = 0; ci < 4; ++ci)
            #pragma unroll
            for (int si = 0; si < 5; ++si)
                acc[ci][si] += __shfl_xor(acc[ci][si], m);
        #pragma unroll
        for (int si = 0; si < 5; ++si)
            qs[si] += __shfl_xor(qs[si], m);
    }

    if (lane == 0) {
        size_t pbase = PPART_OFF + ((size_t)bq * NSLOT + chunk) * CC * SS;
        #pragma unroll
        for (int ci = 0; ci < 4; ++ci)
            #pragma unroll
            for (int si = 0; si < 5; ++si)
                ws[pbase + (size_t)(cbase + ci) * SS + sbase + si] = acc[ci][si];
        if (w == 0) {
            size_t qb2 = QSUM_OFF + ((size_t)bq * NSLOT + chunk) * SS;
            #pragma unroll
            for (int si = 0; si < 5; ++si)
                ws[qb2 + sbase + si] = qs[si];
        }
    }
}

// K3 (fused rels + finalize): per bq, build rels in LDS, reduce partials,
// spf_n[c,s] = (sum_t rels[s,t] P[c,t]) / (sum_t rels[s,t] qsum[t] + eps)
__global__ __launch_bounds__(256) void k_finalize(const float* __restrict__ spf1,
                                                  const float* __restrict__ spf2,
                                                  float* __restrict__ ws) {
    int bq = blockIdx.x;  // 0..7
    int b = bq >> 1, q = bq & 1;
    __shared__ float sp[CC][SS];       // 6.4 KB
    __shared__ float rl[SS][SS + 1];   // 40.4 KB, +1 pad: stride 101 (gcd(5,32)=1)
    __shared__ float P[CC * SS];       // 6.4 KB
    __shared__ float qs[SS];
    __shared__ float den[SS];
    int tid = threadIdx.x;

    const float* spf = (q ? spf2 : spf1) + (size_t)b * CC * SS;
    for (int i = tid; i < CC * SS; i += 256) sp[i / SS][i % SS] = spf[i];
    __syncthreads();
    for (int i = tid; i < SS * SS; i += 256) {
        int s = i / SS, t = i % SS;
        float d2 = 0.f;
        #pragma unroll
        for (int c = 0; c < CC; ++c) {
            float d = sp[c][t] - sp[c][s];
            d2 += d * d;
        }
        rl[s][t] = expf(-d2);
    }

    const float* pp = ws + PPART_OFF + (size_t)bq * NSLOT * CC * SS;
    for (int idx = tid; idx < CC * SS; idx += 256) {
        float a = 0.f;
        for (int ch = 0; ch < NSLOT; ++ch) a += pp[(size_t)ch * CC * SS + idx];
        P[idx] = a;
    }
    const float* qp = ws + QSUM_OFF + (size_t)bq * NSLOT * SS;
    if (tid < SS) {
        float a = 0.f;
        for (int ch = 0; ch < NSLOT; ++ch) a += qp[(size_t)ch * SS + tid];
        qs[tid] = a;
    }
    __syncthreads();
    if (tid < SS) {
        float a = 0.f;
        for (int t = 0; t < SS; ++t) a += rl[tid][t] * qs[t];
        den[tid] = a + EPSV;
    }
    __syncthreads();
    float* sout = ws + SPFN_OFF + (size_t)bq * CC * SS;
    for (int idx = tid; idx < CC * SS; idx += 256) {
        int c = idx / SS, s = idx % SS;
        float a = 0.f;
        for (int t = 0; t < SS; ++t) a += rl[s][t] * P[c * SS + t];
        sout[idx] = a / den[s];
    }
}

// K4: pf_sp[c,n] = sum_s spf1n[c,s] Q1[s,n] + spf2n[c,s] Q2[s,n]
// Thread owns 4 consecutive pixels (float4); spf_n staged transposed in LDS.
__global__ __launch_bounds__(256) void k_pass2(const float* __restrict__ Q1,
                                               const float* __restrict__ Q2,
                                               float* __restrict__ ws) {
    int blk = blockIdx.x;   // 0..N/1024-1
    int b   = blockIdx.y;
    __shared__ float sp[2][SS][CC];
    int tid = threadIdx.x;
    const float* spin = ws + SPFN_OFF + (size_t)b * 2 * CC * SS;
    for (int idx = tid; idx < 2 * CC * SS; idx += 256) {
        int qq  = idx / (CC * SS);
        int rem = idx % (CC * SS);
        int c = rem / SS, s = rem % SS;
        sp[qq][s][c] = spin[idx];
    }
    __syncthreads();
    int n = blk * 1024 + tid * 4;
    const float* q1p = Q1 + (size_t)b * SS * NN + n;
    const float* q2p = Q2 + (size_t)b * SS * NN + n;
    float4 acc[CC];
    #pragma unroll
    for (int c = 0; c < CC; ++c) acc[c] = make_float4(0.f, 0.f, 0.f, 0.f);
    #pragma unroll 2
    for (int s = 0; s < SS; ++s) {
        float4 v1 = *(const float4*)(q1p + (size_t)s * NN);
        float4 v2 = *(const float4*)(q2p + (size_t)s * NN);
        #pragma unroll
        for (int g = 0; g < 4; ++g) {
            float4 s1v = *(const float4*)&sp[0][s][g * 4];
            float4 s2v = *(const float4*)&sp[1][s][g * 4];
            fma4(acc[g * 4 + 0], s1v.x, v1); fma4(acc[g * 4 + 0], s2v.x, v2);
            fma4(acc[g * 4 + 1], s1v.y, v1); fma4(acc[g * 4 + 1], s2v.y, v2);
            fma4(acc[g * 4 + 2], s1v.z, v1); fma4(acc[g * 4 + 2], s2v.z, v2);
            fma4(acc[g * 4 + 3], s1v.w, v1); fma4(acc[g * 4 + 3], s2v.w, v2);
        }
    }
    float* o = ws + PFSP_OFF + (size_t)b * CC * NN + n;
    #pragma unroll
    for (int c = 0; c < CC; ++c)
        *(float4*)(o + (size_t)c * NN) = acc[c];
}

// K5: 3x3 conv (cross-correlation, SAME zero padding), 16 -> 2 channels, + bias
__global__ __launch_bounds__(256) void k_conv(const float* __restrict__ w_ds,
                                              const float* __restrict__ b_ds,
                                              const float* __restrict__ ws,
                                              float* __restrict__ out) {
    int b = blockIdx.y;
    int n = blockIdx.x * 256 + threadIdx.x;
    __shared__ float wl[2][CC][9];
    __shared__ float bl[2];
    for (int i = threadIdx.x; i < 2 * CC * 9; i += 256)
        ((float*)wl)[i] = w_ds[i];
    if (threadIdx.x < 2) bl[threadIdx.x] = b_ds[threadIdx.x];
    __syncthreads();
    int y = n >> 8, x = n & 255;
    const float* base = ws + PFSP_OFF + (size_t)b * CC * NN;
    float a0 = bl[0], a1 = bl[1];
    for (int c = 0; c < CC; ++c) {
        const float* pc = base + (size_t)c * NN;
        #pragma unroll
        for (int dy = -1; dy <= 1; ++dy) {
            int yy = y + dy;
            if (yy < 0 || yy >= HH) continue;
            #pragma unroll
            for (int dx = -1; dx <= 1; ++dx) {
                int xx = x + dx;
                if (xx < 0 || xx >= WW) continue;
                float v = pc[(size_t)yy * WW + xx];
                int k = (dy + 1) * 3 + (dx + 1);
                a0 += v * wl[0][c][k];
                a1 += v * wl[1][c][k];
            }
        }
    }
    out[((size_t)b * 2 + 0) * NN + n] = a0;
    out[((size_t)b * 2 + 1) * NN + n] = a1;
}

extern "C" void kernel_launch(void* const* d_in, const int* in_sizes, int n_in,
                              void* d_out, int out_size, void* d_ws, size_t ws_size,
                              hipStream_t stream) {
    const float* pf   = (const float*)d_in[0];
    const float* spf1 = (const float*)d_in[1];
    const float* spf2 = (const float*)d_in[2];
    const float* Q1   = (const float*)d_in[3];
    const float* Q2   = (const float*)d_in[4];
    const float* w_ds = (const float*)d_in[5];
    const float* b_ds = (const float*)d_in[6];
    float* ws  = (float*)d_ws;
    float* out = (float*)d_out;

    k_pass1<<<dim3(20, 16, 8), 256, 0, stream>>>(pf, Q1, Q2, ws);
    k_finalize<<<8, 256, 0, stream>>>(spf1, spf2, ws);
    k_pass2<<<dim3(NN / 1024, BB), 256, 0, stream>>>(Q1, Q2, ws);
    k_conv<<<dim3(NN / 256, BB), 256, 0, stream>>>(w_ds, b_ds, ws, out);
}